// Round 3
// baseline (262.797 us; speedup 1.0000x reference)
//
#include <hip/hip_runtime.h>
#include <float.h>

// Problem constants: B=32 L=1024 D=128 K=1024
#define NTOK 32768
#define DDIM 128
#define KCODES 1024
#define TT 128    // tokens per block
#define KH 512    // codes per block (codebook split across 2 block-halves)
#define KC 128    // codes per K-chunk
#define DC 64     // d per chunk
#define PCH 129   // LDS pitch: makes staging stores AND fragment reads conflict-free

// Optimization barrier: block fma-contraction/reassociation so we replicate
// numpy's exact fp32 rounding sequence (critical for bit-exact argmin).
__device__ __forceinline__ float nofuse(float x) { asm volatile("" : "+v"(x)); return x; }

// ---------------- fused row-norms (numpy pairwise_sum order for n=128) ------
// grid covers z rows then codebook rows: 132*256 == 32768+1024 exactly.
__global__ void rownorm_np(const float* __restrict__ z, const float* __restrict__ cb,
                           float* __restrict__ znorm, float* __restrict__ cnorm) {
    int row = blockIdx.x * blockDim.x + threadIdx.x;
    const float* p;
    float* outp;
    if (row < NTOK) { p = z + (size_t)row * DDIM; outp = znorm + row; }
    else            { p = cb + (size_t)(row - NTOK) * DDIM; outp = cnorm + (row - NTOK); }
    float r[8];
    #pragma unroll
    for (int j = 0; j < 8; ++j) { float v = p[j]; r[j] = nofuse(v * v); }
    #pragma unroll
    for (int i = 8; i < DDIM; i += 8) {
        #pragma unroll
        for (int j = 0; j < 8; ++j) {
            float v = p[i + j];
            r[j] = nofuse(r[j] + nofuse(v * v));
        }
    }
    float s01 = nofuse(r[0] + r[1]);
    float s23 = nofuse(r[2] + r[3]);
    float s45 = nofuse(r[4] + r[5]);
    float s67 = nofuse(r[6] + r[7]);
    *outp = nofuse(nofuse(s01 + s23) + nofuse(s45 + s67));
}

// ---------------- distances + argmin over this block's 512 codes -----------
// dist(t,k) = fl( fl(zn_t + cn_k) - 2*dot(z_t,c_k) )  — numpy fp32 semantics.
// 8x8 micro-tile: 64 FMA per 4 ds_read_b128. Register-prefetch of next stage's
// global data overlaps the 64-d FMA loop (hides HBM/L2 latency across barrier).
__global__ __launch_bounds__(256, 2)
void dist_argmin(const float* __restrict__ z, const float* __restrict__ cb,
                 const float* __restrict__ znorm, const float* __restrict__ cnorm,
                 float* __restrict__ minv_out, int* __restrict__ mini_out) {
    __shared__ float zt[DC * PCH];   // [d][token], pitch 129
    __shared__ float ct[DC * PCH];   // [d][code]
    __shared__ float cn_s[KC];
    __shared__ float zn_s[TT];

    const int tid = threadIdx.x;
    const int tx = tid & 15;    // code micro-col base
    const int ty = tid >> 4;    // token micro-row base
    const int tile = blockIdx.x & 255;
    const int half = blockIdx.x >> 8;
    const int t0 = tile * TT;
    const int kbase = half * KH;

    if (tid < TT) zn_s[tid] = znorm[t0 + tid];

    // prefetch registers for one (kc,dc) stage: 8 float4 of z-half, 8 of cb-half
    float4 vz[8], vc[8];
    {
        #pragma unroll
        for (int it = 0; it < 8; ++it) {
            int g = it * 256 + tid;
            int r = g >> 4, d4 = g & 15;              // r: token/code row 0..127
            vz[it] = *(const float4*)(z + (size_t)(t0 + r) * DDIM + 4 * d4);
            vc[it] = *(const float4*)(cb + (size_t)(kbase + r) * DDIM + 4 * d4);
        }
    }

    float minv[8];
    int   mini[8];
    #pragma unroll
    for (int i = 0; i < 8; ++i) { minv[i] = FLT_MAX; mini[i] = 0; }

    float acc[8][8];

    for (int stage = 0; stage < 8; ++stage) {
        const int kc = stage >> 1;
        const int dc = stage & 1;
        __syncthreads();   // previous inner loop done — LDS free
        // store prefetched regs, transposed. bank = (4*d4+s+r) mod 32 over a
        // wave (d4 0..15 x r 4 consecutive) -> 2-way = free.
        #pragma unroll
        for (int it = 0; it < 8; ++it) {
            int g = it * 256 + tid;
            int r = g >> 4, d4 = g & 15;
            zt[(4 * d4 + 0) * PCH + r] = vz[it].x;
            zt[(4 * d4 + 1) * PCH + r] = vz[it].y;
            zt[(4 * d4 + 2) * PCH + r] = vz[it].z;
            zt[(4 * d4 + 3) * PCH + r] = vz[it].w;
            ct[(4 * d4 + 0) * PCH + r] = vc[it].x;
            ct[(4 * d4 + 1) * PCH + r] = vc[it].y;
            ct[(4 * d4 + 2) * PCH + r] = vc[it].z;
            ct[(4 * d4 + 3) * PCH + r] = vc[it].w;
        }
        if (dc == 0 && tid < KC) cn_s[tid] = cnorm[kbase + kc * KC + tid];
        __syncthreads();

        // prefetch next stage (overlaps the FMA loop below)
        if (stage + 1 < 8) {
            int ns = stage + 1;
            int nkc = ns >> 1, ndc = ns & 1;
            int koff = kbase + nkc * KC;
            int doff = ndc * DC;
            #pragma unroll
            for (int it = 0; it < 8; ++it) {
                int g = it * 256 + tid;
                int r = g >> 4, d4 = g & 15;
                vz[it] = *(const float4*)(z + (size_t)(t0 + r) * DDIM + doff + 4 * d4);
                vc[it] = *(const float4*)(cb + (size_t)(koff + r) * DDIM + doff + 4 * d4);
            }
        }

        if (dc == 0) {
            #pragma unroll
            for (int i = 0; i < 8; ++i)
                #pragma unroll
                for (int j = 0; j < 8; ++j) acc[i][j] = 0.0f;
        }

        #pragma unroll 2
        for (int d = 0; d < DC; ++d) {
            // zt reads broadcast (16 lanes/address); ct reads 2-way = free
            float4 a0 = *(const float4*)(zt + d * PCH + 4 * ty);
            float4 a1 = *(const float4*)(zt + d * PCH + 64 + 4 * ty);
            float4 b0 = *(const float4*)(ct + d * PCH + 4 * tx);
            float4 b1 = *(const float4*)(ct + d * PCH + 64 + 4 * tx);
            float ar[8] = {a0.x, a0.y, a0.z, a0.w, a1.x, a1.y, a1.z, a1.w};
            float br[8] = {b0.x, b0.y, b0.z, b0.w, b1.x, b1.y, b1.z, b1.w};
            #pragma unroll
            for (int i = 0; i < 8; ++i)
                #pragma unroll
                for (int j = 0; j < 8; ++j)
                    acc[i][j] = fmaf(ar[i], br[j], acc[i][j]);
        }

        if (dc == 1) {
            // full dot ready — numpy-rounded distance + min update.
            // j ascending visits ascending code indices per thread; strict <
            // keeps earliest -> lowest-index tie-break locally.
            #pragma unroll
            for (int j = 0; j < 8; ++j) {
                int cl = (j < 4) ? (4 * tx + j) : (64 + 4 * tx + (j - 4));
                float cn = cn_s[cl];
                int code = kbase + kc * KC + cl;
                #pragma unroll
                for (int i = 0; i < 8; ++i) {
                    int tl = (i < 4) ? (4 * ty + i) : (64 + 4 * ty + (i - 4));
                    float s = nofuse(zn_s[tl] + cn);
                    float dist = fmaf(-2.0f, acc[i][j], s);  // 2*acc exact
                    if (dist < minv[i]) { minv[i] = dist; mini[i] = code; }
                }
            }
        }
    }

    // cross-thread reduction: 16 tx-threads per token, lowest-index ties
    __syncthreads();
    float* red_v = zt;          // [TT][16]
    int*   red_i = (int*)ct;    // [TT][16]
    #pragma unroll
    for (int i = 0; i < 8; ++i) {
        int tl = (i < 4) ? (4 * ty + i) : (64 + 4 * ty + (i - 4));
        red_v[tl * 16 + tx] = minv[i];
        red_i[tl * 16 + tx] = mini[i];
    }
    __syncthreads();
    if (tid < TT) {
        float bv = red_v[tid * 16];
        int   bi = red_i[tid * 16];
        #pragma unroll
        for (int j = 1; j < 16; ++j) {
            float v  = red_v[tid * 16 + j];
            int   ii = red_i[tid * 16 + j];
            if (v < bv || (v == bv && ii < bi)) { bv = v; bi = ii; }
        }
        minv_out[half * NTOK + t0 + tid] = bv;
        mini_out[half * NTOK + t0 + tid] = bi;
    }
}

// ---------------- merge halves + gather z_q + loss accumulation ------------
__global__ void gather_loss(const float* __restrict__ z, const float* __restrict__ cb,
                            const float* __restrict__ minv_part, const int* __restrict__ mini_part,
                            float* __restrict__ zq, float* __restrict__ idxf,
                            float* __restrict__ loss_accum) {
    int g = blockIdx.x * 256 + threadIdx.x;
    int token = g >> 5;
    int q4 = g & 31;
    float v0 = minv_part[token];
    float v1 = minv_part[NTOK + token];
    int   i0 = mini_part[token];
    int   i1 = mini_part[NTOK + token];
    int k = (v1 < v0) ? i1 : i0;   // tie -> half0 (lower index) — numpy argmin
    float4 q  = *(const float4*)(cb + (size_t)k * DDIM + 4 * q4);
    float4 zv = *(const float4*)(z + (size_t)token * DDIM + 4 * q4);
    *(float4*)(zq + (size_t)token * DDIM + 4 * q4) = q;
    if (q4 == 0) idxf[token] = (float)k;
    float dx = q.x - zv.x, dy = q.y - zv.y, dz = q.z - zv.z, dw = q.w - zv.w;
    float s = dx * dx + dy * dy + dz * dz + dw * dw;
    #pragma unroll
    for (int off = 32; off > 0; off >>= 1) s += __shfl_down(s, off);
    __shared__ float sm[4];
    int lane = threadIdx.x & 63, wv = threadIdx.x >> 6;
    if (lane == 0) sm[wv] = s;
    __syncthreads();
    if (threadIdx.x == 0) atomicAdd(loss_accum, sm[0] + sm[1] + sm[2] + sm[3]);
}

__global__ void loss_final(const float* __restrict__ loss_accum, float* __restrict__ out_loss) {
    if (threadIdx.x == 0)
        out_loss[0] = (float)((double)loss_accum[0] * 1.25 / (double)((size_t)NTOK * DDIM));
}

extern "C" void kernel_launch(void* const* d_in, const int* in_sizes, int n_in,
                              void* d_out, int out_size, void* d_ws, size_t ws_size,
                              hipStream_t stream) {
    const float* z  = (const float*)d_in[0];   // [32768,128]
    const float* cb = (const float*)d_in[1];   // [1024,128]
    float* out  = (float*)d_out;
    float* zq   = out;                         // 4194304
    float* loss = out + (size_t)NTOK * DDIM;   // 1
    float* idxf = loss + 1;                    // 32768

    float* znorm      = (float*)d_ws;                    // 32768
    float* cnorm      = znorm + NTOK;                    // 1024
    float* minv_part  = cnorm + KCODES;                  // 2*32768
    int*   mini_part  = (int*)(minv_part + 2 * NTOK);    // 2*32768
    float* loss_accum = (float*)(mini_part + 2 * NTOK);  // 1

    hipMemsetAsync(loss_accum, 0, sizeof(float), stream);
    rownorm_np<<<(NTOK + KCODES) / 256, 256, 0, stream>>>(z, cb, znorm, cnorm);
    dist_argmin<<<512, 256, 0, stream>>>(z, cb, znorm, cnorm, minv_part, mini_part);
    gather_loss<<<NTOK * 32 / 256, 256, 0, stream>>>(z, cb, minv_part, mini_part,
                                                     zq, idxf, loss_accum);
    loss_final<<<1, 64, 0, stream>>>(loss_accum, loss);
}